// Round 5
// baseline (43.950 us; speedup 1.0000x reference)
//
#include <hip/hip_runtime.h>

#define NB    128           // DTW block size N
#define NCH   64            // channels
#define ROWB  260           // bytes per sD row: 128 h16 + 2 pad h16
#define LOG2E 1.4426950408889634f
#define LN2   0.6931471805599453f
#define LARGE 1e9f

typedef _Float16 h16;
typedef __attribute__((ext_vector_type(2))) _Float16 h16x2;
typedef __attribute__((ext_vector_type(8))) _Float16 h16x8;
typedef __attribute__((ext_vector_type(4))) float    f32x4;

static __device__ __forceinline__ float ex2(float x) {
#if __has_builtin(__builtin_amdgcn_exp2f)
    return __builtin_amdgcn_exp2f(x);
#else
    return exp2f(x);
#endif
}

static __device__ __forceinline__ float lg2(float x) {
#if __has_builtin(__builtin_amdgcn_logf)
    return __builtin_amdgcn_logf(x);   // v_log_f32 = log2
#else
    return log2f(x);
#endif
}

// lane t gets lane t-1's src; lane 0 gets `fill`. Pure VALU (DPP wave_shr:1).
static __device__ __forceinline__ float shift_up1(float src, float fill) {
    int r = __builtin_amdgcn_update_dpp(__builtin_bit_cast(int, fill),
                                        __builtin_bit_cast(int, src),
                                        0x138 /*wave_shr:1*/, 0xf, 0xf, false);
    return __builtin_bit_cast(float, r);
}

// soft-min of 3 in log2 domain + D*log2e (gamma=1, exact w.r.t. reference).
static __device__ __forceinline__ float softmin3(float a, float b, float c, float Dv) {
    float m = fminf(fminf(a, b), c);
    float M = fmaxf(fmaxf(a, b), c);
#if __has_builtin(__builtin_amdgcn_fmed3f)
    float e = __builtin_amdgcn_fmed3f(a, b, c);
#else
    float e = ((a + b) + c) - m - M;
#endif
    float s = 1.0f + (ex2(m - e) + ex2(m - M));
    return fmaf(Dv, LOG2E, m - lg2(s));
}

__global__ __launch_bounds__(64, 1)
void dtw_k(const float* __restrict__ X, const float* __restrict__ Y,
           float* __restrict__ out, int nbpb)
{
    __shared__ h16   sD[NB * (ROWB / 2)];   // 33280 B, D row-major fp16, stride 260 B
    __shared__ float sx2[NB];               // 512 B

    const int w = blockIdx.x;               // block-pair id
    const int t = threadIdx.x;              // 0..63
    const int c = t & 15, g = t >> 4;       // MFMA fragment coords
    char* sDb = (char*)sD;
    const float* gx = X + (size_t)w * (NB * NCH);
    const float* gy = Y + (size_t)w * (NB * NCH);

    // ---- zero-fill ALL of sD (incl. pads): fused schedule reads not-yet-written
    // rows out-of-window; init 0 keeps every junk read finite >= 0 (containment).
    {
        uint4 zz = {0u, 0u, 0u, 0u};
        #pragma unroll
        for (int i = 0; i < 32; ++i)
            *(uint4*)(sDb + 1024 * i + 16 * t) = zz;   // 32 KiB
        if (t < 32)
            *(uint4*)(sDb + 32768 + 16 * t) = zz;      // last 512 B (33280 total)
    }

    // ---- B fragments (y rows as MFMA B operand) + y2 norms, all in registers.
    h16x8 Bf[8][2];
    float y2r[8];
    #pragma unroll
    for (int J = 0; J < 8; ++J) {
        const float* py = gy + (16 * J + c) * NCH + 8 * g;
        float p = 0.f;
        #pragma unroll
        for (int q = 0; q < 2; ++q) {
            float4 a = *(const float4*)(py + 32 * q);
            float4 b = *(const float4*)(py + 32 * q + 4);
            h16x8 h;
            h[0]=(h16)a.x; h[1]=(h16)a.y; h[2]=(h16)a.z; h[3]=(h16)a.w;
            h[4]=(h16)b.x; h[5]=(h16)b.y; h[6]=(h16)b.z; h[7]=(h16)b.w;
            Bf[J][q] = h;
            p = fmaf(a.x,a.x,p); p = fmaf(a.y,a.y,p);
            p = fmaf(a.z,a.z,p); p = fmaf(a.w,a.w,p);
            p = fmaf(b.x,b.x,p); p = fmaf(b.y,b.y,p);
            p = fmaf(b.z,b.z,p); p = fmaf(b.w,b.w,p);
        }
        p += __shfl_xor(p, 16, 64);
        p += __shfl_xor(p, 32, 64);
        y2r[J] = p;                          // ||y[16J+c]||^2
    }

    // ---- A-fragment prefetch registers (tile I data lives in nx before TILE(I))
    float4 nx0, nx1, nx2, nx3;
    {
        const float* px = gx + c * NCH + 8 * g;
        nx0 = *(const float4*)(px);
        nx1 = *(const float4*)(px + 4);
        nx2 = *(const float4*)(px + 32);
        nx3 = *(const float4*)(px + 36);
    }

    // TILE(I): consume nx -> A frags + x2; prefetch tile I+1; 16 MFMAs; D epilogue
    #define TILE(Iexp) { \
        const int I_ = (Iexp); \
        float4 a0 = nx0, a1 = nx1, a2 = nx2, a3 = nx3; \
        if (I_ < 7) { \
            const float* px = gx + (16 * (I_ + 1) + c) * NCH + 8 * g; \
            nx0 = *(const float4*)(px); \
            nx1 = *(const float4*)(px + 4); \
            nx2 = *(const float4*)(px + 32); \
            nx3 = *(const float4*)(px + 36); \
        } \
        h16x8 Af0, Af1; \
        Af0[0]=(h16)a0.x; Af0[1]=(h16)a0.y; Af0[2]=(h16)a0.z; Af0[3]=(h16)a0.w; \
        Af0[4]=(h16)a1.x; Af0[5]=(h16)a1.y; Af0[6]=(h16)a1.z; Af0[7]=(h16)a1.w; \
        Af1[0]=(h16)a2.x; Af1[1]=(h16)a2.y; Af1[2]=(h16)a2.z; Af1[3]=(h16)a2.w; \
        Af1[4]=(h16)a3.x; Af1[5]=(h16)a3.y; Af1[6]=(h16)a3.z; Af1[7]=(h16)a3.w; \
        float p_ = 0.f; \
        p_=fmaf(a0.x,a0.x,p_); p_=fmaf(a0.y,a0.y,p_); p_=fmaf(a0.z,a0.z,p_); p_=fmaf(a0.w,a0.w,p_); \
        p_=fmaf(a1.x,a1.x,p_); p_=fmaf(a1.y,a1.y,p_); p_=fmaf(a1.z,a1.z,p_); p_=fmaf(a1.w,a1.w,p_); \
        p_=fmaf(a2.x,a2.x,p_); p_=fmaf(a2.y,a2.y,p_); p_=fmaf(a2.z,a2.z,p_); p_=fmaf(a2.w,a2.w,p_); \
        p_=fmaf(a3.x,a3.x,p_); p_=fmaf(a3.y,a3.y,p_); p_=fmaf(a3.z,a3.z,p_); p_=fmaf(a3.w,a3.w,p_); \
        p_ += __shfl_xor(p_, 16, 64); \
        p_ += __shfl_xor(p_, 32, 64); \
        sx2[16 * I_ + c] = p_; \
        f32x4 acc_[8]; \
        _Pragma("unroll") \
        for (int J = 0; J < 8; ++J) { \
            f32x4 z = {0.f, 0.f, 0.f, 0.f}; \
            z = __builtin_amdgcn_mfma_f32_16x16x32_f16(Af0, Bf[J][0], z, 0, 0, 0); \
            z = __builtin_amdgcn_mfma_f32_16x16x32_f16(Af1, Bf[J][1], z, 0, 0, 0); \
            acc_[J] = z; \
        } \
        float4 x2v = *(const float4*)&sx2[16 * I_ + 4 * g]; \
        float xa_[4] = {x2v.x, x2v.y, x2v.z, x2v.w}; \
        _Pragma("unroll") \
        for (int J = 0; J < 8; ++J) { \
            char* base_ = sDb + 2 * (16 * J + c) + ROWB * (16 * I_ + 4 * g); \
            float y2v_ = y2r[J]; \
            _Pragma("unroll") \
            for (int r = 0; r < 4; ++r) { \
                float dv_ = fmaf(-2.0f, acc_[J][r], xa_[r] + y2v_); \
                *(h16*)(base_ + ROWB * r) = (h16)dv_; \
            } \
        } }

    // ---- prologue: tile 0 must exist before DP chunk 0
    TILE(0)

    // ---- DP state & helpers (negative-offset window trick, lane t owns rows 2t/2t+1)
    const int baseA = 516 * t;          // row 2t byte base minus 4t (window shift)
    const int baseB = 516 * t + 260;

    h16x2 nA[8], nB[8];
    #define LOAD8(dst, off) { \
        const h16x2* p_ = (const h16x2*)(sDb + (off)); \
        _Pragma("unroll") for (int q = 0; q < 8; ++q) (dst)[q] = p_[q]; }

    LOAD8(nA, baseA)
    LOAD8(nB, baseB)

    float fA[16], fB[16];
    float r1a = LARGE, r1b = LARGE, r2a = LARGE;
    float dg_prev = (t == 0) ? 0.0f : LARGE;   // corner R[-1][-1]=0 feeds cell (0,0)
    float carryB = 0.0f;

    #define CONVERT() { _Pragma("unroll") for (int q = 0; q < 8; ++q) { \
        fA[2*q] = (float)nA[q][0]; fA[2*q+1] = (float)nA[q][1]; \
        fB[2*q] = (float)nB[q][0]; fB[2*q+1] = (float)nB[q][1]; } }

    #define STEP(D0v, D1v) { \
        float up_cur = shift_up1(r1b, LARGE); \
        float n0 = softmin3(r1a, up_cur, dg_prev, (D0v)); \
        float n1 = softmin3(r1b, r1a, r2a, (D1v)); \
        r2a = r1a; r1a = n0; r1b = n1; dg_prev = up_cur; }

    // ---- fused main loop: DP chunk cc + D-tile cc+1 (tiles 1..7 under chunks 0..6)
    for (int cc = 0; cc < 15; ++cc) {
        CONVERT()                       // chunk cc data -> f32 regs
        if (cc < 7) TILE(cc + 1)        // independent MFMA/pack stream fills DP bubbles
        LOAD8(nA, baseA + 32 * (cc + 1))   // after tile writes: same-wave DS is in-order
        LOAD8(nB, baseB + 32 * (cc + 1))
        #pragma unroll
        for (int k = 0; k < 16; ++k) {
            float D1v = (k == 0) ? carryB : fB[k - 1];
            STEP(fA[k], D1v)
        }
        carryB = fB[15];
    }
    CONVERT()
    #pragma unroll
    for (int k = 0; k < 15; ++k) {      // d = 240..254; lane63 r1b ends as R~[127][127]
        float D1v = (k == 0) ? carryB : fB[k - 1];
        STEP(fA[k], D1v)
    }

    if (t == 63) {
        atomicAdd(&out[w / nbpb], r1b * LN2);   // back to natural-log domain
    }
}

extern "C" void kernel_launch(void* const* d_in, const int* in_sizes, int n_in,
                              void* d_out, int out_size, void* d_ws, size_t ws_size,
                              hipStream_t stream) {
    const float* x = (const float*)d_in[0];
    const float* y = (const float*)d_in[1];
    float* out = (float*)d_out;

    const int nblk = in_sizes[0] / (NB * NCH);   // 1024 block-pairs
    const int nbpb = nblk / out_size;            // 32 blocks per batch

    hipMemsetAsync(out, 0, (size_t)out_size * sizeof(float), stream);
    dtw_k<<<nblk, 64, 0, stream>>>(x, y, out, nbpb);
}

// Round 6
// 42.998 us; speedup vs baseline: 1.0221x; 1.0221x over previous
//
#include <hip/hip_runtime.h>

#define NB    128           // DTW block size N
#define NCH   64            // channels
#define ROWB  260           // bytes per sD row: 128 h16 + 2 pad h16
#define LOG2E 1.4426950408889634f
#define LN2   0.6931471805599453f
#define LARGE 1e9f

typedef _Float16 h16;
typedef __attribute__((ext_vector_type(2))) _Float16 h16x2;
typedef __attribute__((ext_vector_type(8))) _Float16 h16x8;
typedef __attribute__((ext_vector_type(4))) float    f32x4;

static __device__ __forceinline__ float ex2(float x) {
#if __has_builtin(__builtin_amdgcn_exp2f)
    return __builtin_amdgcn_exp2f(x);
#else
    return exp2f(x);
#endif
}

static __device__ __forceinline__ float lg2(float x) {
#if __has_builtin(__builtin_amdgcn_logf)
    return __builtin_amdgcn_logf(x);   // v_log_f32 = log2
#else
    return log2f(x);
#endif
}

// lane t gets lane t-1's src; lane 0 gets `fill`. Pure VALU (DPP wave_shr:1).
static __device__ __forceinline__ float shift_up1(float src, float fill) {
    int r = __builtin_amdgcn_update_dpp(__builtin_bit_cast(int, fill),
                                        __builtin_bit_cast(int, src),
                                        0x138 /*wave_shr:1*/, 0xf, 0xf, false);
    return __builtin_bit_cast(float, r);
}

// soft-min of 3 in log2 domain + D*log2e (gamma=1, exact w.r.t. reference).
static __device__ __forceinline__ float softmin3(float a, float b, float c, float Dv) {
    float m = fminf(fminf(a, b), c);
    float M = fmaxf(fmaxf(a, b), c);
#if __has_builtin(__builtin_amdgcn_fmed3f)
    float e = __builtin_amdgcn_fmed3f(a, b, c);
#else
    float e = ((a + b) + c) - m - M;
#endif
    float s = 1.0f + (ex2(m - e) + ex2(m - M));
    return fmaf(Dv, LOG2E, m - lg2(s));
}

__global__ __launch_bounds__(128, 2)
void dtw_k(const float* __restrict__ X, const float* __restrict__ Y,
           float* __restrict__ out, int nbpb)
{
    // 2 waves/wg: wave 1 = producer (loads + MFMA -> D tiles into LDS, 2 ahead),
    // wave 0 = consumer (anti-diagonal DP). 2048 waves total = 2 waves/SIMD TLP.
    __shared__ h16   sD[NB * (ROWB / 2)];   // 33280 B, D fp16, stride 260 B
    __shared__ float sx2[NB];               // 512 B (producer-private)

    const int w   = blockIdx.x;             // block-pair id
    const int tid = threadIdx.x;            // 0..127
    const int wid = tid >> 6;               // 0 = consumer, 1 = producer
    const int t   = tid & 63;               // lane in wave
    char* sDb = (char*)sD;
    const float* gx = X + (size_t)w * (NB * NCH);
    const float* gy = Y + (size_t)w * (NB * NCH);

    if (wid == 1) {
        // ================= PRODUCER =================
        const int c = t & 15, g = t >> 4;   // MFMA fragment coords

        // zero pads (cols 128,129) of rows 0..31 (consumer fills rows 32..127)
        if (t < 32) *(unsigned*)(sDb + ROWB * t + 256) = 0u;

        // B fragments (y as MFMA B operand) + y2 norms, in registers
        h16x8 Bf[8][2];
        float y2r[8];
        #pragma unroll
        for (int J = 0; J < 8; ++J) {
            const float* py = gy + (16 * J + c) * NCH + 8 * g;
            float p = 0.f;
            #pragma unroll
            for (int q = 0; q < 2; ++q) {
                float4 a = *(const float4*)(py + 32 * q);
                float4 b = *(const float4*)(py + 32 * q + 4);
                h16x8 h;
                h[0]=(h16)a.x; h[1]=(h16)a.y; h[2]=(h16)a.z; h[3]=(h16)a.w;
                h[4]=(h16)b.x; h[5]=(h16)b.y; h[6]=(h16)b.z; h[7]=(h16)b.w;
                Bf[J][q] = h;
                p = fmaf(a.x,a.x,p); p = fmaf(a.y,a.y,p);
                p = fmaf(a.z,a.z,p); p = fmaf(a.w,a.w,p);
                p = fmaf(b.x,b.x,p); p = fmaf(b.y,b.y,p);
                p = fmaf(b.z,b.z,p); p = fmaf(b.w,b.w,p);
            }
            p += __shfl_xor(p, 16, 64);
            p += __shfl_xor(p, 32, 64);
            y2r[J] = p;                      // ||y[16J+c]||^2
        }

        // A-tile prefetch regs (tile I data lives in nx before TILE(I))
        float4 nx0, nx1, nx2, nx3;
        {
            const float* px = gx + c * NCH + 8 * g;
            nx0 = *(const float4*)(px);
            nx1 = *(const float4*)(px + 4);
            nx2 = *(const float4*)(px + 32);
            nx3 = *(const float4*)(px + 36);
        }

        #define TILE(Iexp) { \
            const int I_ = (Iexp); \
            float4 a0 = nx0, a1 = nx1, a2 = nx2, a3 = nx3; \
            if (I_ < 7) { \
                const float* px = gx + (16 * (I_ + 1) + c) * NCH + 8 * g; \
                nx0 = *(const float4*)(px); \
                nx1 = *(const float4*)(px + 4); \
                nx2 = *(const float4*)(px + 32); \
                nx3 = *(const float4*)(px + 36); \
            } \
            h16x8 Af0, Af1; \
            Af0[0]=(h16)a0.x; Af0[1]=(h16)a0.y; Af0[2]=(h16)a0.z; Af0[3]=(h16)a0.w; \
            Af0[4]=(h16)a1.x; Af0[5]=(h16)a1.y; Af0[6]=(h16)a1.z; Af0[7]=(h16)a1.w; \
            Af1[0]=(h16)a2.x; Af1[1]=(h16)a2.y; Af1[2]=(h16)a2.z; Af1[3]=(h16)a2.w; \
            Af1[4]=(h16)a3.x; Af1[5]=(h16)a3.y; Af1[6]=(h16)a3.z; Af1[7]=(h16)a3.w; \
            float p_ = 0.f; \
            p_=fmaf(a0.x,a0.x,p_); p_=fmaf(a0.y,a0.y,p_); p_=fmaf(a0.z,a0.z,p_); p_=fmaf(a0.w,a0.w,p_); \
            p_=fmaf(a1.x,a1.x,p_); p_=fmaf(a1.y,a1.y,p_); p_=fmaf(a1.z,a1.z,p_); p_=fmaf(a1.w,a1.w,p_); \
            p_=fmaf(a2.x,a2.x,p_); p_=fmaf(a2.y,a2.y,p_); p_=fmaf(a2.z,a2.z,p_); p_=fmaf(a2.w,a2.w,p_); \
            p_=fmaf(a3.x,a3.x,p_); p_=fmaf(a3.y,a3.y,p_); p_=fmaf(a3.z,a3.z,p_); p_=fmaf(a3.w,a3.w,p_); \
            p_ += __shfl_xor(p_, 16, 64); \
            p_ += __shfl_xor(p_, 32, 64); \
            sx2[16 * I_ + c] = p_; \
            f32x4 acc_[8]; \
            _Pragma("unroll") \
            for (int J = 0; J < 8; ++J) { \
                f32x4 z = {0.f, 0.f, 0.f, 0.f}; \
                z = __builtin_amdgcn_mfma_f32_16x16x32_f16(Af0, Bf[J][0], z, 0, 0, 0); \
                z = __builtin_amdgcn_mfma_f32_16x16x32_f16(Af1, Bf[J][1], z, 0, 0, 0); \
                acc_[J] = z; \
            } \
            float4 x2v = *(const float4*)&sx2[16 * I_ + 4 * g]; \
            float xa_[4] = {x2v.x, x2v.y, x2v.z, x2v.w}; \
            _Pragma("unroll") \
            for (int J = 0; J < 8; ++J) { \
                char* base_ = sDb + 2 * (16 * J + c) + ROWB * (16 * I_ + 4 * g); \
                float y2v_ = y2r[J]; \
                _Pragma("unroll") \
                for (int r = 0; r < 4; ++r) { \
                    float dv_ = fmaf(-2.0f, acc_[J][r], xa_[r] + y2v_); \
                    *(h16*)(base_ + ROWB * r) = (h16)dv_; \
                } \
            } }

        TILE(0)
        TILE(1)
        __syncthreads();                    // bar0: tiles 0,1 ready
        for (int s = 0; s < 16; ++s) {      // stay 2 tiles ahead of DP chunk s
            if (s < 6) TILE(s + 2)
            __syncthreads();
        }
        // producer done (17 barriers total)
    } else {
        // ================= CONSUMER =================
        // zero-fill rows 32..127 (bytes 8320..33280): all racy/unwritten reads
        // must be finite >= 0 (round-4 lesson: garbage can be NaN/-Inf)
        {
            uint4 zz = {0u, 0u, 0u, 0u};
            #pragma unroll
            for (int i = 0; i < 25; ++i) {
                int off = 8320 + 1024 * i + 16 * t;
                if (off < 33280) *(uint4*)(sDb + off) = zz;
            }
        }
        __syncthreads();                    // bar0: tiles 0,1 ready

        const int baseA = 516 * t;          // row 2t base minus 4t (window shift)
        const int baseB = 516 * t + 260;

        h16x2 nA[8], nB[8];
        #define LOAD8(dst, off) { \
            const h16x2* p_ = (const h16x2*)(sDb + (off)); \
            _Pragma("unroll") for (int q = 0; q < 8; ++q) (dst)[q] = p_[q]; }

        LOAD8(nA, baseA)
        LOAD8(nB, baseB)

        float fA[16], fB[16];
        float r1a = LARGE, r1b = LARGE, r2a = LARGE;
        float dg_prev = (t == 0) ? 0.0f : LARGE;  // corner R[-1][-1]=0
        float carryB = 0.0f;

        #define CONVERT() { _Pragma("unroll") for (int q = 0; q < 8; ++q) { \
            fA[2*q] = (float)nA[q][0]; fA[2*q+1] = (float)nA[q][1]; \
            fB[2*q] = (float)nB[q][0]; fB[2*q+1] = (float)nB[q][1]; } }

        #define STEP(D0v, D1v) { \
            float up_cur = shift_up1(r1b, LARGE); \
            float n0 = softmin3(r1a, up_cur, dg_prev, (D0v)); \
            float n1 = softmin3(r1b, r1a, r2a, (D1v)); \
            r2a = r1a; r1a = n0; r1b = n1; dg_prev = up_cur; }

        for (int cc = 0; cc < 15; ++cc) {
            CONVERT()                       // chunk cc -> f32 regs
            LOAD8(nA, baseA + 32 * (cc + 1))   // prefetch chunk cc+1 (tile cc+1
            LOAD8(nB, baseB + 32 * (cc + 1))   // ready since bar(cc-1))
            #pragma unroll
            for (int k = 0; k < 16; ++k) {
                float D1v = (k == 0) ? carryB : fB[k - 1];
                STEP(fA[k], D1v)
            }
            carryB = fB[15];
            __syncthreads();                // bar(cc): producer tile cc+2 done
        }
        CONVERT()
        #pragma unroll
        for (int k = 0; k < 15; ++k) {      // d = 240..254
            float D1v = (k == 0) ? carryB : fB[k - 1];
            STEP(fA[k], D1v)
        }
        __syncthreads();                    // final barrier (17 total)

        if (t == 63) {
            atomicAdd(&out[w / nbpb], r1b * LN2);
        }
    }
}

extern "C" void kernel_launch(void* const* d_in, const int* in_sizes, int n_in,
                              void* d_out, int out_size, void* d_ws, size_t ws_size,
                              hipStream_t stream) {
    const float* x = (const float*)d_in[0];
    const float* y = (const float*)d_in[1];
    float* out = (float*)d_out;

    const int nblk = in_sizes[0] / (NB * NCH);   // 1024 block-pairs
    const int nbpb = nblk / out_size;            // 32 blocks per batch

    hipMemsetAsync(out, 0, (size_t)out_size * sizeof(float), stream);
    dtw_k<<<nblk, 128, 0, stream>>>(x, y, out, nbpb);
}

// Round 7
// 42.671 us; speedup vs baseline: 1.0300x; 1.0077x over previous
//
#include <hip/hip_runtime.h>

#define NB    128           // DTW block size N
#define NCH   64            // channels
#define ROWB  256           // bytes per sD row: 128 h16, NO pad (LDS must fit 32 KiB)
#define LOG2E 1.4426950408889634f
#define LN2   0.6931471805599453f
#define LARGE 1e9f

typedef _Float16 h16;
typedef __attribute__((ext_vector_type(2))) _Float16 h16x2;
typedef __attribute__((ext_vector_type(8))) _Float16 h16x8;
typedef __attribute__((ext_vector_type(4))) float    f32x4;

static __device__ __forceinline__ float ex2(float x) {
#if __has_builtin(__builtin_amdgcn_exp2f)
    return __builtin_amdgcn_exp2f(x);
#else
    return exp2f(x);
#endif
}

static __device__ __forceinline__ float lg2(float x) {
#if __has_builtin(__builtin_amdgcn_logf)
    return __builtin_amdgcn_logf(x);   // v_log_f32 = log2
#else
    return log2f(x);
#endif
}

// lane t gets lane t-1's src; lane 0 gets `fill`. Pure VALU (DPP wave_shr:1).
static __device__ __forceinline__ float shift_up1(float src, float fill) {
    int r = __builtin_amdgcn_update_dpp(__builtin_bit_cast(int, fill),
                                        __builtin_bit_cast(int, src),
                                        0x138 /*wave_shr:1*/, 0xf, 0xf, false);
    return __builtin_bit_cast(float, r);
}

// soft-min of 3 in log2 domain + D*log2e (gamma=1, exact w.r.t. reference).
static __device__ __forceinline__ float softmin3(float a, float b, float c, float Dv) {
    float m = fminf(fminf(a, b), c);
    float M = fmaxf(fmaxf(a, b), c);
#if __has_builtin(__builtin_amdgcn_fmed3f)
    float e = __builtin_amdgcn_fmed3f(a, b, c);
#else
    float e = ((a + b) + c) - m - M;
#endif
    float s = 1.0f + (ex2(m - e) + ex2(m - M));
    return fmaf(Dv, LOG2E, m - lg2(s));
}

__global__ __launch_bounds__(64, 1)
void dtw_k(const float* __restrict__ X, const float* __restrict__ Y,
           float* __restrict__ out, int nbpb)
{
    __shared__ h16 sD[NB * (ROWB / 2)];     // 32768 B exactly -> 4 wgs/CU @128KB budget

    const int w = blockIdx.x;               // block-pair id
    const int t = threadIdx.x;              // 0..63
    const int c = t & 15, g = t >> 4;       // MFMA fragment coords
    char* sDb = (char*)sD;
    const float* gx = X + (size_t)w * (NB * NCH);
    const float* gy = Y + (size_t)w * (NB * NCH);

    // ---- zero-fill sD: fused schedule reads not-yet-written rows out-of-window;
    // init 0 keeps every junk read finite >= 0 (round-4 lesson).
    {
        uint4 zz = {0u, 0u, 0u, 0u};
        #pragma unroll
        for (int i = 0; i < 32; ++i)
            *(uint4*)(sDb + 1024 * i + 16 * t) = zz;   // 32 KiB exactly
    }

    // ---- B fragments (y rows as MFMA B operand) + y2 norms, all in registers.
    h16x8 Bf[8][2];
    float y2r[8];
    #pragma unroll
    for (int J = 0; J < 8; ++J) {
        const float* py = gy + (16 * J + c) * NCH + 8 * g;
        float p = 0.f;
        #pragma unroll
        for (int q = 0; q < 2; ++q) {
            float4 a = *(const float4*)(py + 32 * q);
            float4 b = *(const float4*)(py + 32 * q + 4);
            h16x8 h;
            h[0]=(h16)a.x; h[1]=(h16)a.y; h[2]=(h16)a.z; h[3]=(h16)a.w;
            h[4]=(h16)b.x; h[5]=(h16)b.y; h[6]=(h16)b.z; h[7]=(h16)b.w;
            Bf[J][q] = h;
            p = fmaf(a.x,a.x,p); p = fmaf(a.y,a.y,p);
            p = fmaf(a.z,a.z,p); p = fmaf(a.w,a.w,p);
            p = fmaf(b.x,b.x,p); p = fmaf(b.y,b.y,p);
            p = fmaf(b.z,b.z,p); p = fmaf(b.w,b.w,p);
        }
        p += __shfl_xor(p, 16, 64);
        p += __shfl_xor(p, 32, 64);
        y2r[J] = p;                          // ||y[16J+c]||^2
    }

    // ---- A-fragment prefetch registers (tile I data lives in nx before TILE(I))
    float4 nx0, nx1, nx2, nx3;
    {
        const float* px = gx + c * NCH + 8 * g;
        nx0 = *(const float4*)(px);
        nx1 = *(const float4*)(px + 4);
        nx2 = *(const float4*)(px + 32);
        nx3 = *(const float4*)(px + 36);
    }

    // TILE(I): consume nx -> A frags + x2; prefetch tile I+1; 16 MFMAs; D epilogue.
    // x2 row norms distributed via shfl (no LDS): lane holds ||x[16I+c]||^2 after
    // the xor-reduce; epilogue needs rows 16I+4g+p -> __shfl from lane 4g+p.
    #define TILE(Iexp) { \
        const int I_ = (Iexp); \
        float4 a0 = nx0, a1 = nx1, a2 = nx2, a3 = nx3; \
        if (I_ < 7) { \
            const float* px = gx + (16 * (I_ + 1) + c) * NCH + 8 * g; \
            nx0 = *(const float4*)(px); \
            nx1 = *(const float4*)(px + 4); \
            nx2 = *(const float4*)(px + 32); \
            nx3 = *(const float4*)(px + 36); \
        } \
        h16x8 Af0, Af1; \
        Af0[0]=(h16)a0.x; Af0[1]=(h16)a0.y; Af0[2]=(h16)a0.z; Af0[3]=(h16)a0.w; \
        Af0[4]=(h16)a1.x; Af0[5]=(h16)a1.y; Af0[6]=(h16)a1.z; Af0[7]=(h16)a1.w; \
        Af1[0]=(h16)a2.x; Af1[1]=(h16)a2.y; Af1[2]=(h16)a2.z; Af1[3]=(h16)a2.w; \
        Af1[4]=(h16)a3.x; Af1[5]=(h16)a3.y; Af1[6]=(h16)a3.z; Af1[7]=(h16)a3.w; \
        float p_ = 0.f; \
        p_=fmaf(a0.x,a0.x,p_); p_=fmaf(a0.y,a0.y,p_); p_=fmaf(a0.z,a0.z,p_); p_=fmaf(a0.w,a0.w,p_); \
        p_=fmaf(a1.x,a1.x,p_); p_=fmaf(a1.y,a1.y,p_); p_=fmaf(a1.z,a1.z,p_); p_=fmaf(a1.w,a1.w,p_); \
        p_=fmaf(a2.x,a2.x,p_); p_=fmaf(a2.y,a2.y,p_); p_=fmaf(a2.z,a2.z,p_); p_=fmaf(a2.w,a2.w,p_); \
        p_=fmaf(a3.x,a3.x,p_); p_=fmaf(a3.y,a3.y,p_); p_=fmaf(a3.z,a3.z,p_); p_=fmaf(a3.w,a3.w,p_); \
        p_ += __shfl_xor(p_, 16, 64); \
        p_ += __shfl_xor(p_, 32, 64); \
        float xa_[4]; \
        xa_[0] = __shfl(p_, 4 * g + 0, 64); \
        xa_[1] = __shfl(p_, 4 * g + 1, 64); \
        xa_[2] = __shfl(p_, 4 * g + 2, 64); \
        xa_[3] = __shfl(p_, 4 * g + 3, 64); \
        f32x4 acc_[8]; \
        _Pragma("unroll") \
        for (int J = 0; J < 8; ++J) { \
            f32x4 z = {0.f, 0.f, 0.f, 0.f}; \
            z = __builtin_amdgcn_mfma_f32_16x16x32_f16(Af0, Bf[J][0], z, 0, 0, 0); \
            z = __builtin_amdgcn_mfma_f32_16x16x32_f16(Af1, Bf[J][1], z, 0, 0, 0); \
            acc_[J] = z; \
        } \
        _Pragma("unroll") \
        for (int J = 0; J < 8; ++J) { \
            char* base_ = sDb + 2 * (16 * J + c) + ROWB * (16 * I_ + 4 * g); \
            float y2v_ = y2r[J]; \
            _Pragma("unroll") \
            for (int r = 0; r < 4; ++r) { \
                float dv_ = fmaf(-2.0f, acc_[J][r], xa_[r] + y2v_); \
                *(h16*)(base_ + ROWB * r) = (h16)dv_; \
            } \
        } }

    // ---- prologue: tile 0 must exist before DP chunk 0
    TILE(0)

    // ---- DP state & helpers (negative-offset window trick, lane t owns rows 2t/2t+1)
    const int baseA = 508 * t;          // row 2t byte base (512t) minus 4t (window shift)
    const int baseB = 508 * t + 256;

    h16x2 nA[8], nB[8];
    #define LOAD8(dst, off) { \
        const h16x2* p_ = (const h16x2*)(sDb + (off)); \
        _Pragma("unroll") for (int q = 0; q < 8; ++q) (dst)[q] = p_[q]; }

    LOAD8(nA, baseA)
    LOAD8(nB, baseB)

    float fA[16], fB[16];
    float r1a = LARGE, r1b = LARGE, r2a = LARGE;
    float dg_prev = (t == 0) ? 0.0f : LARGE;   // corner R[-1][-1]=0 feeds cell (0,0)
    float carryB = 0.0f;

    #define CONVERT() { _Pragma("unroll") for (int q = 0; q < 8; ++q) { \
        fA[2*q] = (float)nA[q][0]; fA[2*q+1] = (float)nA[q][1]; \
        fB[2*q] = (float)nB[q][0]; fB[2*q+1] = (float)nB[q][1]; } }

    #define STEP(D0v, D1v) { \
        float up_cur = shift_up1(r1b, LARGE); \
        float n0 = softmin3(r1a, up_cur, dg_prev, (D0v)); \
        float n1 = softmin3(r1b, r1a, r2a, (D1v)); \
        r2a = r1a; r1a = n0; r1b = n1; dg_prev = up_cur; }

    // ---- fused main loop: DP chunk cc + D-tile cc+1 (tiles 1..7 under chunks 0..6)
    for (int cc = 0; cc < 15; ++cc) {
        CONVERT()                       // chunk cc data -> f32 regs
        if (cc < 7) TILE(cc + 1)        // independent MFMA/pack stream fills DP bubbles
        LOAD8(nA, baseA + 32 * (cc + 1))   // after tile writes: same-wave DS is in-order
        LOAD8(nB, baseB + 32 * (cc + 1))
        #pragma unroll
        for (int k = 0; k < 16; ++k) {
            float D1v = (k == 0) ? carryB : fB[k - 1];
            STEP(fA[k], D1v)
        }
        carryB = fB[15];
    }
    CONVERT()
    #pragma unroll
    for (int k = 0; k < 15; ++k) {      // d = 240..254; lane63 r1b ends as R~[127][127]
        float D1v = (k == 0) ? carryB : fB[k - 1];
        STEP(fA[k], D1v)
    }

    if (t == 63) {
        atomicAdd(&out[w / nbpb], r1b * LN2);   // back to natural-log domain
    }
}

extern "C" void kernel_launch(void* const* d_in, const int* in_sizes, int n_in,
                              void* d_out, int out_size, void* d_ws, size_t ws_size,
                              hipStream_t stream) {
    const float* x = (const float*)d_in[0];
    const float* y = (const float*)d_in[1];
    float* out = (float*)d_out;

    const int nblk = in_sizes[0] / (NB * NCH);   // 1024 block-pairs
    const int nbpb = nblk / out_size;            // 32 blocks per batch

    hipMemsetAsync(out, 0, (size_t)out_size * sizeof(float), stream);
    dtw_k<<<nblk, 64, 0, stream>>>(x, y, out, nbpb);
}